// Round 3
// baseline (616.916 us; speedup 1.0000x reference)
//
#include <hip/hip_runtime.h>

// Persistent-kernel Sinkhorn (scaling form): K = exp(-C/eps) lives in LDS
// (9 rows x 2304 x 4B = 83KB per block, 1 block/CU, 256 blocks).
// All 10 scaling updates + final cost run in ONE kernel with a device-scope
// atomic grid barrier (release/acquire fences for cross-XCD visibility).
//   a' = m_src .* a ./ (a .* (K b) + 1e-6);  b' = m_tgt .* b ./ (b .* (K a') + 1e-6)
//   cost_b = sum_i a_i * sum_j (K.C)_ij * b_j,  C recomputed as -eps*ln(K).

#define SN 2304
#define SNF4 576
#define NBAT 32
#define ROWS 9        // SN / 256 blocks
#define NTHR 512
#define NBLK 256
#define NWIN 36       // SN / 64-j windows
#define KF (ROWS * SN)           // 20736 floats of K in LDS
#define LDS_BYTES ((KF + 2304 + 288) * 4)   // K + S_part(8*288) + c_lds(288)

__device__ __forceinline__ void fma4(float4& a, float k, const float4 x) {
    a.x = fmaf(k, x.x, a.x);
    a.y = fmaf(k, x.y, a.y);
    a.z = fmaf(k, x.z, a.z);
    a.w = fmaf(k, x.w, a.w);
}

__global__ __launch_bounds__(256) void k_sums(const float* __restrict__ pred,
                                              const float* __restrict__ tgt,
                                              float* __restrict__ psum,
                                              float* __restrict__ tsum) {
    const int b = blockIdx.x & 31;
    const bool isP = blockIdx.x < 32;
    const float* src = (isP ? pred : tgt) + (size_t)b * 3 * SN;
    const int t = threadIdx.x;
    float acc = 0.f;
    for (int i = t; i < SN; i += 256) acc += src[i] + 1e-9f;
    #pragma unroll
    for (int off = 32; off; off >>= 1) acc += __shfl_down(acc, off);
    __shared__ float red[4];
    if ((t & 63) == 0) red[t >> 6] = acc;
    __syncthreads();
    if (t == 0) (isP ? psum : tsum)[b] = red[0] + red[1] + red[2] + red[3];
}

__global__ __launch_bounds__(256) void k_minit(const float* __restrict__ pred,
                                               const float* __restrict__ tgt,
                                               const float* __restrict__ psum,
                                               const float* __restrict__ tsum,
                                               float* __restrict__ msrc,
                                               float* __restrict__ mtgt,
                                               int* __restrict__ bar) {
    const int b = blockIdx.x;
    const float ps = psum[b], ts = tsum[b];
    #pragma unroll
    for (int k = 0; k < 9; ++k) {
        const int i = threadIdx.x + k * 256;
        const float pv = pred[(size_t)b * 3 * SN + i];
        const float tv = tgt[(size_t)b * 3 * SN + i];
        msrc[(size_t)i * NBAT + b] = (pv + 1e-9f) / ps;
        mtgt[(size_t)i * NBAT + b] = (tv + 1e-9f) / ts;
    }
    if (b == 0 && threadIdx.x < 16) bar[threadIdx.x] = 0;
}

__device__ __forceinline__ void gbar(int* bar, int p) {
    __syncthreads();
    if (threadIdx.x == 0) {
        __threadfence();   // release: wb dirty L2 -> LLC
        __hip_atomic_fetch_add(&bar[p], 1, __ATOMIC_RELAXED, __HIP_MEMORY_SCOPE_AGENT);
        while (__hip_atomic_load(&bar[p], __ATOMIC_RELAXED, __HIP_MEMORY_SCOPE_AGENT) < NBLK)
            __builtin_amdgcn_s_sleep(2);
        __threadfence();   // acquire: invalidate stale L1/L2
    }
    __syncthreads();
}

// MODE 0: build K from C (x implicit ones), update yupd (first=true)
// MODE 1: S = K*x, yupd = mvec.*yold./(yold.*S + 1e-6)
// MODE 2: S = (K.C)*x with C=-eps*ln(K), part[blk][b] = sum_r a*S
template <int MODE>
__device__ void pass_body(float* __restrict__ K_lds, float* __restrict__ S_part,
                          float* __restrict__ c_lds,
                          const float4* __restrict__ Cf4,
                          const float4* __restrict__ xf4,
                          const float* __restrict__ mvec,
                          const float* __restrict__ yold, bool first,
                          float* __restrict__ yupd,
                          const float* __restrict__ avec,
                          float* __restrict__ part, int r0) {
    const int t = threadIdx.x;
    const int w = t >> 6, l = t & 63, jl = l & 15, bl = l >> 4;
    const int wbeg = (NWIN * w) >> 3, wend = (NWIN * (w + 1)) >> 3;

    float4 acc[ROWS][2];
    #pragma unroll
    for (int r = 0; r < ROWS; ++r) {
        acc[r][0] = make_float4(0.f, 0.f, 0.f, 0.f);
        acc[r][1] = make_float4(0.f, 0.f, 0.f, 0.f);
    }

    float4 xq[2][8];
    if (MODE != 0) {
        #pragma unroll
        for (int jj = 0; jj < 4; ++jj)
            #pragma unroll
            for (int h = 0; h < 2; ++h)
                xq[0][jj * 2 + h] = xf4[(size_t)(wbeg * 64 + jl * 4 + jj) * 8 + bl * 2 + h];
    }

    int pb = 0;
    for (int win = wbeg; win < wend; ++win, pb ^= 1) {
        if (MODE != 0 && win + 1 < wend) {
            #pragma unroll
            for (int jj = 0; jj < 4; ++jj)
                #pragma unroll
                for (int h = 0; h < 2; ++h)
                    xq[pb ^ 1][jj * 2 + h] =
                        xf4[(size_t)((win + 1) * 64 + jl * 4 + jj) * 8 + bl * 2 + h];
        }
        if (MODE == 0) {
            float4 cv[ROWS];
            #pragma unroll
            for (int r = 0; r < ROWS; ++r)
                cv[r] = Cf4[(size_t)(r0 + r) * SNF4 + win * 16 + jl];
            #pragma unroll
            for (int r = 0; r < ROWS; ++r) {
                float4 kv;
                kv.x = __expf(cv[r].x * -100.f);
                kv.y = __expf(cv[r].y * -100.f);
                kv.z = __expf(cv[r].z * -100.f);
                kv.w = __expf(cv[r].w * -100.f);
                if (bl == 0) *(float4*)&K_lds[r * SN + win * 64 + jl * 4] = kv;
                acc[r][0].x += (kv.x + kv.y) + (kv.z + kv.w);
            }
        } else {
            #pragma unroll
            for (int r = 0; r < ROWS; ++r) {
                float4 kc = *(const float4*)&K_lds[r * SN + win * 64 + jl * 4];
                if (MODE == 2) {   // K.C = -eps * K * ln(K); K==0 -> 0
                    kc.x = (kc.x > 0.f) ? kc.x * __logf(kc.x) * -0.01f : 0.f;
                    kc.y = (kc.y > 0.f) ? kc.y * __logf(kc.y) * -0.01f : 0.f;
                    kc.z = (kc.z > 0.f) ? kc.z * __logf(kc.z) * -0.01f : 0.f;
                    kc.w = (kc.w > 0.f) ? kc.w * __logf(kc.w) * -0.01f : 0.f;
                }
                const float4* xc = xq[pb];
                fma4(acc[r][0], kc.x, xc[0]); fma4(acc[r][1], kc.x, xc[1]);
                fma4(acc[r][0], kc.y, xc[2]); fma4(acc[r][1], kc.y, xc[3]);
                fma4(acc[r][0], kc.z, xc[4]); fma4(acc[r][1], kc.z, xc[5]);
                fma4(acc[r][0], kc.w, xc[6]); fma4(acc[r][1], kc.w, xc[7]);
            }
        }
    }

    // reduce over 16 j-lanes
    if (MODE == 0) {
        #pragma unroll
        for (int r = 0; r < ROWS; ++r) {
            float s = acc[r][0].x;
            #pragma unroll
            for (int off = 1; off <= 8; off <<= 1) s += __shfl_down(s, off);
            acc[r][0] = make_float4(s, s, s, s);
            acc[r][1] = acc[r][0];
        }
    } else {
        #pragma unroll
        for (int r = 0; r < ROWS; ++r)
            #pragma unroll
            for (int h = 0; h < 2; ++h) {
                float4 a = acc[r][h];
                #pragma unroll
                for (int off = 1; off <= 8; off <<= 1) {
                    a.x += __shfl_down(a.x, off);
                    a.y += __shfl_down(a.y, off);
                    a.z += __shfl_down(a.z, off);
                    a.w += __shfl_down(a.w, off);
                }
                acc[r][h] = a;
            }
    }
    if (jl == 0) {
        #pragma unroll
        for (int r = 0; r < ROWS; ++r) {
            *(float4*)&S_part[w * 288 + r * 32 + bl * 8] = acc[r][0];
            *(float4*)&S_part[w * 288 + r * 32 + bl * 8 + 4] = acc[r][1];
        }
    }
    __syncthreads();

    if (MODE == 2) {
        if (t < 288) {
            float s = 0.f;
            #pragma unroll
            for (int ww = 0; ww < 8; ++ww) s += S_part[ww * 288 + t];
            c_lds[t] = avec[(size_t)(r0 + (t >> 5)) * NBAT + (t & 31)] * s;
        }
        __syncthreads();
        if (t < 32) {
            float p = 0.f;
            #pragma unroll
            for (int r = 0; r < ROWS; ++r) p += c_lds[r * 32 + t];
            part[blockIdx.x * NBAT + t] = p;
        }
    } else {
        if (t < 288) {
            float s = 0.f;
            #pragma unroll
            for (int ww = 0; ww < 8; ++ww) s += S_part[ww * 288 + t];
            const size_t yi = (size_t)(r0 + (t >> 5)) * NBAT + (t & 31);
            const float yo = first ? 1.f : yold[yi];
            yupd[yi] = mvec[yi] * yo / (yo * s + 1e-6f);
        }
    }
}

__global__ __launch_bounds__(NTHR, 2) void k_persist(
        const float* __restrict__ C,
        const float* __restrict__ msrc, const float* __restrict__ mtgt,
        float* __restrict__ ya, float* __restrict__ yb,
        float* __restrict__ part, int* __restrict__ bar) {
    extern __shared__ float lds[];
    float* K_lds  = lds;
    float* S_part = lds + KF;
    float* c_lds  = S_part + 2304;
    const int r0 = blockIdx.x * ROWS;
    const float4* Cf4 = (const float4*)C;

    // pass 0: build K (exp), S=K*1, a = msrc/(S+1e-6)
    pass_body<0>(K_lds, S_part, c_lds, Cf4, nullptr, msrc, nullptr, true, ya, nullptr, nullptr, r0);
    gbar(bar, 0);
    // pass 1: S=K*a, b = mtgt/(S+1e-6)
    pass_body<1>(K_lds, S_part, c_lds, nullptr, (const float4*)ya, mtgt, nullptr, true, yb, nullptr, nullptr, r0);
    gbar(bar, 1);
    int bi = 2;
    for (int it = 1; it < 5; ++it) {
        pass_body<1>(K_lds, S_part, c_lds, nullptr, (const float4*)yb, msrc, ya, false, ya, nullptr, nullptr, r0);
        gbar(bar, bi++);
        pass_body<1>(K_lds, S_part, c_lds, nullptr, (const float4*)ya, mtgt, yb, false, yb, nullptr, nullptr, r0);
        gbar(bar, bi++);
    }
    // final: S=(K.C)*b, part = a .* S summed over block rows
    pass_body<2>(K_lds, S_part, c_lds, nullptr, (const float4*)yb, nullptr, nullptr, false, nullptr, ya, part, r0);
}

__global__ __launch_bounds__(256) void k_out(const float* __restrict__ part,
                                             float* __restrict__ out) {
    __shared__ float l[256];
    const int t = threadIdx.x;
    const int b = t & 31, g = t >> 5;
    float s = 0.f;
    for (int k = g; k < NBLK; k += 8) s += part[(size_t)k * NBAT + b];
    l[t] = s;
    __syncthreads();
    if (t < 32) {
        float o = 0.f;
        #pragma unroll
        for (int g2 = 0; g2 < 8; ++g2) o += l[g2 * 32 + t];
        out[t] = o;
    }
}

extern "C" void kernel_launch(void* const* d_in, const int* in_sizes, int n_in,
                              void* d_out, int out_size, void* d_ws, size_t ws_size,
                              hipStream_t stream) {
    const float* pred = (const float*)d_in[0];
    const float* tgt  = (const float*)d_in[1];
    const float* C    = (const float*)d_in[2];
    float* out = (float*)d_out;

    float* ws = (float*)d_ws;
    float* m_src = ws;                             // SN*32
    float* m_tgt = m_src + (size_t)SN * NBAT;
    float* ya    = m_tgt + (size_t)SN * NBAT;
    float* yb    = ya + (size_t)SN * NBAT;
    float* psum  = yb + (size_t)SN * NBAT;         // 32
    float* tsum  = psum + NBAT;                    // 32
    float* part  = tsum + NBAT;                    // 256*32
    int*   bar   = (int*)(part + (size_t)NBLK * NBAT);  // 16

    hipFuncSetAttribute((const void*)k_persist,
                        hipFuncAttributeMaxDynamicSharedMemorySize, LDS_BYTES);

    k_sums<<<64, 256, 0, stream>>>(pred, tgt, psum, tsum);
    k_minit<<<32, 256, 0, stream>>>(pred, tgt, psum, tsum, m_src, m_tgt, bar);
    k_persist<<<NBLK, NTHR, LDS_BYTES, stream>>>(C, m_src, m_tgt, ya, yb, part, bar);
    k_out<<<1, 256, 0, stream>>>(part, out);
}

// Round 4
// 432.101 us; speedup vs baseline: 1.4277x; 1.4277x over previous
//
#include <hip/hip_runtime.h>

// Persistent-kernel Sinkhorn (scaling form), 3 dispatches total:
//   k_init (zero barrier slots), k_persist (everything), k_out (reduce cost).
// K = exp(-C/eps) built once into a block-PRIVATE global stripe (9 rows/block,
// L2-resident; refetched from LLC after barrier invalidates). No LDS for K,
// no register double-buffers beyond one window -> no scratch spills.
//   a' = m_src .* a ./ (a .* (K b) + 1e-6);  b' = m_tgt .* b ./ (b .* (K a') + 1e-6)
//   cost_b = sum_i a_i * sum_j (K.C)_ij b_j   (K.C recomputed from C)

#define SN 2304
#define SNF4 576
#define NBAT 32
#define ROWS 9
#define NBLK 256
#define NTHR 512
#define NWIN 72      // 32-j windows
#define WPW 9        // windows per wave (8 waves)

__device__ __forceinline__ void fma4(float4& a, float k, const float4 x) {
    a.x = fmaf(k, x.x, a.x);
    a.y = fmaf(k, x.y, a.y);
    a.z = fmaf(k, x.z, a.z);
    a.w = fmaf(k, x.w, a.w);
}

__global__ __launch_bounds__(64) void k_init(int* __restrict__ bar) {
    if (threadIdx.x < 16) bar[threadIdx.x] = 0;
}

__device__ __forceinline__ void gbar(int* bar, int p) {
    __syncthreads();
    if (threadIdx.x == 0) {
        __threadfence();   // release: wb dirty L2 -> LLC
        __hip_atomic_fetch_add(&bar[p], 1, __ATOMIC_RELAXED, __HIP_MEMORY_SCOPE_AGENT);
        while (__hip_atomic_load(&bar[p], __ATOMIC_RELAXED, __HIP_MEMORY_SCOPE_AGENT) < NBLK)
            __builtin_amdgcn_s_sleep(2);
        __threadfence();   // acquire: invalidate L1/L2
    }
    __syncthreads();
}

// MODE 0: Mrow=C stripe; kv=exp(-100*C); store K stripe; x==1; update epilogue
// MODE 1: Mrow=K stripe; x from xf4; update epilogue
// MODE 2: Mrow=C stripe; kv=C*exp(-100*C); x from xf4; cost epilogue
template <int MODE>
__device__ void pass_body(const float4* __restrict__ Mrow,   // (C or K) + r0*SNF4
                          float4* __restrict__ Krow,          // MODE0: K + r0*SNF4
                          const float4* __restrict__ xf4,
                          const float* __restrict__ m_sl,     // LDS slice [288]
                          float* __restrict__ y_sl,           // LDS slice [288]
                          bool first,
                          float* __restrict__ yg,             // global y + r0*32
                          const float* __restrict__ a_sl,     // MODE2: a slice
                          float* __restrict__ part_out,       // MODE2: part + blk*32
                          float* __restrict__ S_lds,          // [8*288]
                          float* __restrict__ c_lds) {        // [288]
    const int t = threadIdx.x;
    const int w = t >> 6, l = t & 63;
    const int jl = l & 7, bl = l >> 3;
    const int wbeg = w * WPW, wend = wbeg + WPW;

    float4 acc[ROWS];
    #pragma unroll
    for (int r = 0; r < ROWS; ++r) acc[r] = make_float4(0.f, 0.f, 0.f, 0.f);

    // prefetch window wbeg
    float4 kn[ROWS], xn[4];
    #pragma unroll
    for (int r = 0; r < ROWS; ++r) kn[r] = Mrow[(size_t)r * SNF4 + wbeg * 8 + jl];
    if (MODE != 0) {
        #pragma unroll
        for (int jj = 0; jj < 4; ++jj)
            xn[jj] = xf4[(size_t)(wbeg * 32 + jl * 4 + jj) * 8 + bl];
    }

    for (int win = wbeg; win < wend; ++win) {
        float4 kc[ROWS], xc[4];
        #pragma unroll
        for (int r = 0; r < ROWS; ++r) kc[r] = kn[r];
        if (MODE != 0) {
            #pragma unroll
            for (int jj = 0; jj < 4; ++jj) xc[jj] = xn[jj];
        }
        if (win + 1 < wend) {
            #pragma unroll
            for (int r = 0; r < ROWS; ++r)
                kn[r] = Mrow[(size_t)r * SNF4 + (win + 1) * 8 + jl];
            if (MODE != 0) {
                #pragma unroll
                for (int jj = 0; jj < 4; ++jj)
                    xn[jj] = xf4[(size_t)((win + 1) * 32 + jl * 4 + jj) * 8 + bl];
            }
        }
        #pragma unroll
        for (int r = 0; r < ROWS; ++r) {
            if (MODE == 0) {
                float4 kv;
                kv.x = __expf(kc[r].x * -100.f);
                kv.y = __expf(kc[r].y * -100.f);
                kv.z = __expf(kc[r].z * -100.f);
                kv.w = __expf(kc[r].w * -100.f);
                if (bl == 0) Krow[(size_t)r * SNF4 + win * 8 + jl] = kv;
                acc[r].x += (kv.x + kv.y) + (kv.z + kv.w);
            } else {
                float4 kv = kc[r];
                if (MODE == 2) {
                    kv.x *= __expf(kv.x * -100.f);
                    kv.y *= __expf(kv.y * -100.f);
                    kv.z *= __expf(kv.z * -100.f);
                    kv.w *= __expf(kv.w * -100.f);
                }
                fma4(acc[r], kv.x, xc[0]);
                fma4(acc[r], kv.y, xc[1]);
                fma4(acc[r], kv.z, xc[2]);
                fma4(acc[r], kv.w, xc[3]);
            }
        }
    }

    // reduce over the 8 j-lanes (offsets 1,2,4 inside each 8-lane group)
    #pragma unroll
    for (int r = 0; r < ROWS; ++r) {
        float4 a = acc[r];
        #pragma unroll
        for (int off = 1; off <= 4; off <<= 1) {
            a.x += __shfl_down(a.x, off);
            a.y += __shfl_down(a.y, off);
            a.z += __shfl_down(a.z, off);
            a.w += __shfl_down(a.w, off);
        }
        if (MODE == 0) { float s = a.x; a = make_float4(s, s, s, s); }
        acc[r] = a;
    }
    if (jl == 0) {
        #pragma unroll
        for (int r = 0; r < ROWS; ++r)
            *(float4*)&S_lds[w * 288 + r * 32 + bl * 4] = acc[r];
    }
    __syncthreads();

    if (MODE == 2) {
        if (t < 288) {
            float s = 0.f;
            #pragma unroll
            for (int ww = 0; ww < 8; ++ww) s += S_lds[ww * 288 + t];
            c_lds[t] = a_sl[t] * s;
        }
        __syncthreads();
        if (t < 32) {
            float p = 0.f;
            #pragma unroll
            for (int r = 0; r < ROWS; ++r) p += c_lds[r * 32 + t];
            part_out[t] = p;
        }
    } else {
        if (t < 288) {
            float s = 0.f;
            #pragma unroll
            for (int ww = 0; ww < 8; ++ww) s += S_lds[ww * 288 + t];
            const float yo = first ? 1.f : y_sl[t];
            const float yn = m_sl[t] * yo / (yo * s + 1e-6f);
            y_sl[t] = yn;
            yg[t] = yn;
        }
        __syncthreads();   // protect S_lds before next pass
    }
}

__global__ __launch_bounds__(NTHR, 2) void k_persist(
        const float* __restrict__ C,
        const float* __restrict__ pred, const float* __restrict__ tgt,
        float* __restrict__ Kws,
        float* __restrict__ ya, float* __restrict__ yb,
        float* __restrict__ psum, float* __restrict__ tsum,
        float* __restrict__ part, int* __restrict__ bar) {
    __shared__ float S_lds[8 * 288];
    __shared__ float c_lds[288];
    __shared__ float m_lds[2][288];
    __shared__ float y_lds[2][288];

    const int blk = blockIdx.x;
    const int r0 = blk * ROWS;
    const int t = threadIdx.x;

    // phase A: per-batch mass sums (blocks 0..63)
    if (blk < 64) {
        const int b = blk & 31;
        const float* src = (blk < 32 ? pred : tgt) + (size_t)b * 3 * SN;
        float s = 0.f;
        for (int i = t; i < SN; i += NTHR) s += src[i] + 1e-9f;
        #pragma unroll
        for (int off = 32; off; off >>= 1) s += __shfl_down(s, off);
        if ((t & 63) == 0) c_lds[t >> 6] = s;
        __syncthreads();
        if (t == 0) {
            float tot = 0.f;
            #pragma unroll
            for (int ww = 0; ww < 8; ++ww) tot += c_lds[ww];
            (blk < 32 ? psum : tsum)[b] = tot;
        }
    }
    gbar(bar, 0);

    // phase B: block-local m slices (rows r0..r0+8, all 32 batches)
    if (t < 288) {
        const int r = t >> 5, b = t & 31;
        const size_t off = (size_t)b * 3 * SN + (r0 + r);
        m_lds[0][t] = (pred[off] + 1e-9f) / psum[b];
        m_lds[1][t] = (tgt[off] + 1e-9f) / tsum[b];
    }
    __syncthreads();

    const float4* Cf4 = (const float4*)C + (size_t)r0 * SNF4;
    float4* Kf4 = (float4*)Kws + (size_t)r0 * SNF4;

    // pass 0: build K, S=K*1, a = msrc/(S+1e-6)
    pass_body<0>(Cf4, Kf4, nullptr, m_lds[0], y_lds[0], true,
                 ya + (size_t)r0 * NBAT, nullptr, nullptr, S_lds, c_lds);
    gbar(bar, 1);

    // passes 1..9
    for (int p = 1; p < 10; ++p) {
        const float* xg = (p & 1) ? ya : yb;
        float* yg = (p & 1) ? yb : ya;
        pass_body<1>(Kf4, nullptr, (const float4*)xg, m_lds[p & 1], y_lds[p & 1],
                     p < 2, yg + (size_t)r0 * NBAT, nullptr, nullptr, S_lds, c_lds);
        gbar(bar, 1 + p);
    }

    // cost pass: S = (K.C)*b, part = sum_r a.*S
    pass_body<2>(Cf4, nullptr, (const float4*)yb, nullptr, nullptr, false,
                 nullptr, y_lds[0], part + (size_t)blk * NBAT, S_lds, c_lds);
}

__global__ __launch_bounds__(256) void k_out(const float* __restrict__ part,
                                             float* __restrict__ out) {
    __shared__ float l[256];
    const int t = threadIdx.x;
    const int b = t & 31, g = t >> 5;
    float s = 0.f;
    for (int k = g; k < NBLK; k += 8) s += part[(size_t)k * NBAT + b];
    l[t] = s;
    __syncthreads();
    if (t < 32) {
        float o = 0.f;
        #pragma unroll
        for (int g2 = 0; g2 < 8; ++g2) o += l[g2 * 32 + t];
        out[t] = o;
    }
}

extern "C" void kernel_launch(void* const* d_in, const int* in_sizes, int n_in,
                              void* d_out, int out_size, void* d_ws, size_t ws_size,
                              hipStream_t stream) {
    const float* pred = (const float*)d_in[0];
    const float* tgt  = (const float*)d_in[1];
    const float* C    = (const float*)d_in[2];
    float* out = (float*)d_out;

    float* ws = (float*)d_ws;
    float* Kws  = ws;                                  // SN*SN
    float* ya   = Kws + (size_t)SN * SN;               // SN*32
    float* yb   = ya + (size_t)SN * NBAT;
    float* psum = yb + (size_t)SN * NBAT;              // 32
    float* tsum = psum + NBAT;                         // 32
    float* part = tsum + NBAT;                         // 256*32
    int*   bar  = (int*)(part + (size_t)NBLK * NBAT);  // 16

    k_init<<<1, 64, 0, stream>>>(bar);
    k_persist<<<NBLK, NTHR, 0, stream>>>(C, pred, tgt, Kws, ya, yb,
                                         psum, tsum, part, bar);
    k_out<<<1, 256, 0, stream>>>(part, out);
}